// Round 2
// baseline (316.250 us; speedup 1.0000x reference)
//
#include <hip/hip_runtime.h>

// Head_13: fused single-head causal attention, B=1024 T=128 C=384 HS=64, fp32 I/O.
// One block (4 waves) per batch. bf16 MFMA 32x32x16.
// Phase 1 (QKV proj): barrier-free; W pre-packed to fragment-major bf16 (L2-resident),
// x streamed with register double-buffer. Phase 2: LDS q/k/v, causal flash in-block,
// rowsum via shfl_xor butterfly (no layout assumptions).

typedef __attribute__((ext_vector_type(8)))  short  short8;   // 8 bf16 = 4 VGPR
typedef __attribute__((ext_vector_type(16))) float  floatx16; // MFMA 32x32 acc
typedef __attribute__((ext_vector_type(4)))  float  float4v;

#define T_DIM   128
#define C_DIM   384
#define HS      64
#define NCHUNK  12            // 384/32
#define SLAB    1536          // shorts per (c,ks,half) slab = 192 n * 8 k

#define QK_PITCH 68           // 64+4 bf16 -> 136 B row (8B-aligned, 2-way banks = free)
#define V_PITCH  132          // 128+4 bf16 -> 264 B
#define P_PITCH  132
#define Q_OFF 0
#define K_OFF 17408           // 128*136
#define V_OFF 34816
#define LDS_BYTES 51712       // V_OFF + 64*264
#define P_OFF 0               // P [128][132]*2 = 33792 overlays q + head of k (dead in 2b)

#define MFMA(a,b,c) __builtin_amdgcn_mfma_f32_32x32x16_bf16((a),(b),(c),0,0,0)

__device__ inline unsigned short f2bf(float f){ // fp32 -> bf16 RTNE
    unsigned u = __builtin_bit_cast(unsigned, f);
    u += 0x7FFFu + ((u >> 16) & 1u);
    return (unsigned short)(u >> 16);
}

__device__ inline short8 ld_b64x2(const char* p){ // 16B fragment via two 8B LDS reads
    union { unsigned long long u[2]; short8 s; } r;
    r.u[0] = *(const unsigned long long*)(p);
    r.u[1] = *(const unsigned long long*)(p + 8);
    return r.s;
}

// W[q|k|v] fp32 [384][64] -> wt bf16 fragment-major: [c][ks][half][n=192][j=8]
// short index = ((c*2+ks)*2+half)*1536 + n*8 + j ; k_global = c*32+ks*16+half*8+j
__global__ void prep_wt(const float* __restrict__ Wq, const float* __restrict__ Wk,
                        const float* __restrict__ Wv, unsigned short* __restrict__ wt){
    int idx = blockIdx.x * 256 + threadIdx.x;
    if (idx >= 48 * SLAB) return;
    int slab = idx / SLAB;
    int rem  = idx - slab * SLAB;
    int n = rem >> 3, j = rem & 7;
    int half = slab & 1, ks = (slab >> 1) & 1, c = slab >> 2;
    int kg = c*32 + ks*16 + half*8 + j;
    const float* W = (n < 64) ? Wq : (n < 128) ? Wk : Wv;
    wt[idx] = f2bf(W[kg * HS + (n & 63)]);
}

__launch_bounds__(256, 2)
__global__ void attn_kernel(const float* __restrict__ x,
                            const unsigned short* __restrict__ wtg,
                            float* __restrict__ out){
    __shared__ __align__(16) char smem[LDS_BYTES];
    const int tid  = threadIdx.x;
    const int lane = tid & 63;
    const int wave = tid >> 6;
    const int l31  = lane & 31;
    const int half = lane >> 5;
    const int koff = half * 8;            // MFMA k-split: lanes 32-63 hold k+8..k+15
    const int b    = blockIdx.x;
    const float* xb = x + (size_t)b * (T_DIM * C_DIM);

    // ---------------- phase 1: [q|k|v] = x[b] @ Wt  (no LDS, no barriers) --------
    const int mpair = wave & 1;           // rows 64*mpair .. +63 (2 M-blocks)
    const int ntri  = wave >> 1;          // wt cols 96*ntri .. +95 (3 N-blocks)
    const int mrow0 = 64 * mpair + l31;
    const short8* wf = (const short8*)wtg;
    const int nbase = 96 * ntri + l31;

    floatx16 acc[6] = {};                 // [nbl*2 + mbl]
    float4v bufA[8], bufB[8];             // x double buffer [ks*4+mbl*2+hi]

    auto xload = [&](float4v (&buf)[8], int c){
        #pragma unroll
        for (int ks = 0; ks < 2; ++ks)
            #pragma unroll
            for (int mbl = 0; mbl < 2; ++mbl){
                const float* g = xb + (mrow0 + 32*mbl)*C_DIM + (c*32 + ks*16 + koff);
                buf[ks*4+mbl*2+0] = *(const float4v*)g;
                buf[ks*4+mbl*2+1] = *(const float4v*)(g + 4);
            }
    };
    auto body = [&](int c, float4v (&cur)[8], float4v (&nxt)[8]){
        if (c + 1 < NCHUNK) xload(nxt, c + 1);
        short8 afrag[2][2];
        #pragma unroll
        for (int ks = 0; ks < 2; ++ks)
            #pragma unroll
            for (int mbl = 0; mbl < 2; ++mbl){
                float4v lo = cur[ks*4+mbl*2+0], hi = cur[ks*4+mbl*2+1];
                short8 a;
                a[0]=(short)f2bf(lo[0]); a[1]=(short)f2bf(lo[1]);
                a[2]=(short)f2bf(lo[2]); a[3]=(short)f2bf(lo[3]);
                a[4]=(short)f2bf(hi[0]); a[5]=(short)f2bf(hi[1]);
                a[6]=(short)f2bf(hi[2]); a[7]=(short)f2bf(hi[3]);
                afrag[ks][mbl] = a;
            }
        #pragma unroll
        for (int ks = 0; ks < 2; ++ks){
            const short8* slab = wf + ((c*2 + ks)*2 + half) * 192;
            #pragma unroll
            for (int nbl = 0; nbl < 3; ++nbl){
                short8 bfrag = slab[nbase + 32*nbl];   // aligned 16B, coalesced over l31
                acc[nbl*2+0] = MFMA(afrag[ks][0], bfrag, acc[nbl*2+0]);
                acc[nbl*2+1] = MFMA(afrag[ks][1], bfrag, acc[nbl*2+1]);
            }
        }
    };

    xload(bufA, 0);
    for (int cc = 0; cc < NCHUNK; cc += 2){
        body(cc,     bufA, bufB);
        body(cc + 1, bufB, bufA);
    }

    // write q,k (row-major, softmax scale*log2e folded into q) and v (h-major) to LDS
    const float QSCALE = 0.125f * 1.44269504088896f;
    #pragma unroll
    for (int nbl = 0; nbl < 3; ++nbl)
        #pragma unroll
        for (int mbl = 0; mbl < 2; ++mbl){
            floatx16 A = acc[nbl*2+mbl];
            int nb = 3*ntri + nbl;        // 0..5: q q k k v v
            int mb = 2*mpair + mbl;
            if (nb < 4){
                int base  = (nb < 2) ? Q_OFF : K_OFF;
                int col   = 32 * (nb & 1) + l31;
                float sc  = (nb < 2) ? QSCALE : 1.0f;
                char* bp  = smem + base + col * 2;
                #pragma unroll
                for (int r = 0; r < 16; ++r){
                    int t = 32*mb + (r&3) + 8*(r>>2) + 4*half;   // verified C/D row map
                    *(unsigned short*)(bp + t * (QK_PITCH*2)) = f2bf(A[r] * sc);
                }
            } else {
                int h = 32*(nb-4) + l31;
                char* bp = smem + V_OFF + h * (V_PITCH*2);
                #pragma unroll
                for (int g = 0; g < 4; ++g){
                    int t0 = 32*mb + 8*g + 4*half;   // regs 4g..4g+3 = 4 consecutive rows
                    union { unsigned short s[4]; unsigned long long u; } pk;
                    pk.s[0]=f2bf(A[4*g+0]); pk.s[1]=f2bf(A[4*g+1]);
                    pk.s[2]=f2bf(A[4*g+2]); pk.s[3]=f2bf(A[4*g+3]);
                    *(unsigned long long*)(bp + t0*2) = pk.u;
                }
            }
        }
    __syncthreads();

    // ---------------- phase 2a: S = q k^T (causal), P = exp2(S) ----------------
    // wave w owns rows [32w, 32w+32); tiles st > w fully masked -> skipped.
    floatx16 accS[4] = {};
    #pragma unroll
    for (int ks = 0; ks < 4; ++ks){
        short8 aq = ld_b64x2(smem + Q_OFF + (32*wave + l31)*(QK_PITCH*2) + (ks*16 + koff)*2);
        #pragma unroll
        for (int st = 0; st < 4; ++st)
            if (st <= wave){
                short8 bk = ld_b64x2(smem + K_OFF + (32*st + l31)*(QK_PITCH*2) + (ks*16 + koff)*2);
                accS[st] = MFMA(aq, bk, accS[st]);
            }
    }
    // |logit| <~ 8 -> exp2 safe in fp32 without max-subtraction
    #pragma unroll
    for (int st = 0; st < 4; ++st)
        if (st <= wave){
            #pragma unroll
            for (int r = 0; r < 16; ++r){
                int trow = (r&3) + 8*(r>>2) + 4*half;
                float e = exp2f(accS[st][r]);
                if (st == wave && l31 > trow) e = 0.0f;   // causal mask, diagonal tile
                accS[st][r] = e;
            }
        }

    // rowsum -> 1/l per (reg, half) via butterfly within each 32-lane half.
    // accS[st] for st > wave is still all-zero, so sum all 4 unconditionally.
    float linv[16];
    #pragma unroll
    for (int r = 0; r < 16; ++r){
        float l = accS[0][r] + accS[1][r] + accS[2][r] + accS[3][r];
        #pragma unroll
        for (int m = 1; m <= 16; m <<= 1)
            l += __shfl_xor(l, m);
        linv[r] = 1.0f / l;
    }
    __syncthreads();     // all waves done reading q,k (P overlays them)

    // ---------------- phase 2b: P -> LDS (A-layout), O = P v -------------------
    #pragma unroll
    for (int st = 0; st < 4; ++st)
        if (st <= wave){
            char* bp = smem + P_OFF + (32*st + l31) * 2;
            #pragma unroll
            for (int r = 0; r < 16; ++r){
                int t = 32*wave + (r&3) + 8*(r>>2) + 4*half;
                *(unsigned short*)(bp + t * (P_PITCH*2)) = f2bf(accS[st][r]);
            }
        }
    __syncthreads();

    floatx16 accO0 = {}, accO1 = {};
    const int nks = 2 * (wave + 1);       // P == 0 / unwritten beyond diagonal block
    #pragma unroll
    for (int ks = 0; ks < 8; ++ks)
        if (ks < nks){
            short8 ap  = ld_b64x2(smem + P_OFF + (32*wave + l31)*(P_PITCH*2) + (ks*16 + koff)*2);
            short8 bv0 = ld_b64x2(smem + V_OFF + l31        *(V_PITCH*2) + (ks*16 + koff)*2);
            short8 bv1 = ld_b64x2(smem + V_OFF + (l31 + 32) *(V_PITCH*2) + (ks*16 + koff)*2);
            accO0 = MFMA(ap, bv0, accO0);
            accO1 = MFMA(ap, bv1, accO1);
        }

    // normalize with register-resident 1/l and store fp32 (coalesced over l31)
    float* ob = out + (size_t)b * (T_DIM * HS);
    #pragma unroll
    for (int r = 0; r < 16; ++r){
        int t = 32*wave + (r&3) + 8*(r>>2) + 4*half;
        ob[t*HS + l31]      = accO0[r] * linv[r];
        ob[t*HS + l31 + 32] = accO1[r] * linv[r];
    }
}

extern "C" void kernel_launch(void* const* d_in, const int* in_sizes, int n_in,
                              void* d_out, int out_size, void* d_ws, size_t ws_size,
                              hipStream_t stream){
    const float* x  = (const float*)d_in[0];
    const float* Wq = (const float*)d_in[1];
    const float* Wk = (const float*)d_in[2];
    const float* Wv = (const float*)d_in[3];
    unsigned short* wt = (unsigned short*)d_ws;   // 48*1536*2 = 147456 B used

    prep_wt<<<288, 256, 0, stream>>>(Wq, Wk, Wv, wt);
    attn_kernel<<<1024, 256, 0, stream>>>(x, wt, (float*)d_out);
}